// Round 1
// baseline (3862.278 us; speedup 1.0000x reference)
//
#include <hip/hip_runtime.h>
#include <hip/hip_bf16.h>

#define DEV static __device__ __forceinline__

constexpr int N_  = 8;
constexpr int H_  = 256;
constexpr int W_  = 256;
constexpr int HW_ = H_ * W_;      // 65536
constexpr float EPS_ = 1e-5f;

DEV float toF(float v) { return v; }
DEV float toF(__hip_bfloat16 v) { return __bfloat162float(v); }
DEV float bfbits2f(unsigned short u) { return __uint_as_float(((unsigned)u) << 16); }
DEV unsigned short f2bfbits(float f) {
    __hip_bfloat16 h = __float2bfloat16(f);
    unsigned short b;
    __builtin_memcpy(&b, &h, 2);
    return b;
}

DEV void storeV(float* p, float v) { *p = v; }
DEV void storeV(__hip_bfloat16* p, float v) { *p = __float2bfloat16(v); }

DEV void load4(const float* p, float* v) {
    float4 t = *reinterpret_cast<const float4*>(p);
    v[0]=t.x; v[1]=t.y; v[2]=t.z; v[3]=t.w;
}
DEV void load4(const __hip_bfloat16* p, float* v) {
    ushort4 t = *reinterpret_cast<const ushort4*>(p);
    v[0]=bfbits2f(t.x); v[1]=bfbits2f(t.y); v[2]=bfbits2f(t.z); v[3]=bfbits2f(t.w);
}
DEV void store4(float* p, const float* v) {
    float4 t; t.x=v[0]; t.y=v[1]; t.z=v[2]; t.w=v[3];
    *reinterpret_cast<float4*>(p) = t;
}
DEV void store4(__hip_bfloat16* p, const float* v) {
    ushort4 t; t.x=f2bfbits(v[0]); t.y=f2bfbits(v[1]); t.z=f2bfbits(v[2]); t.w=f2bfbits(v[3]);
    *reinterpret_cast<ushort4*>(p) = t;
}

DEV float mishf(float v) {
    float sp = (v > 20.f) ? v : log1pf(expf(v));
    return v * tanhf(sp);
}

// ---------------------------------------------------------------------------
// 3x3 conv, pad=1, NCHW. Block: 256 thr = 16x16 pixels, 8 output channels.
// x tile (18x18, one ic at a time) staged in LDS; weights via uniform scalar
// loads (SGPR broadcast into v_fma).
// ---------------------------------------------------------------------------
template<int IC, int OC, typename TIN, typename TOUT>
__global__ __launch_bounds__(256) void conv3x3(const TIN* __restrict__ in,
                                               const float* __restrict__ w,
                                               const float* __restrict__ bias,
                                               TOUT* __restrict__ out)
{
    __shared__ float xs[324];                 // 18*18
    const int tid = threadIdx.x;
    const int tx = tid & 15, ty = tid >> 4;
    const int tileX = blockIdx.x & 15, tileY = blockIdx.x >> 4;
    const int ocBase = blockIdx.y * 8;
    const int n = blockIdx.z;
    const int r0 = tileY * 16, c0 = tileX * 16;

    float acc[8];
#pragma unroll
    for (int o = 0; o < 8; ++o) acc[o] = 0.f;

    const TIN* inN = in + (size_t)n * IC * HW_;

    for (int ic = 0; ic < IC; ++ic) {
        __syncthreads();
        for (int i = tid; i < 324; i += 256) {
            int rr = i / 18, cc = i - rr * 18;
            int gr = r0 - 1 + rr, gc = c0 - 1 + cc;
            float v = 0.f;
            if ((unsigned)gr < (unsigned)H_ && (unsigned)gc < (unsigned)W_)
                v = toF(inN[(size_t)ic * HW_ + gr * W_ + gc]);
            xs[i] = v;
        }
        __syncthreads();

        float xv[9];
#pragma unroll
        for (int dy = 0; dy < 3; ++dy)
#pragma unroll
            for (int dx = 0; dx < 3; ++dx)
                xv[dy * 3 + dx] = xs[(ty + dy) * 18 + tx + dx];

        const float* wp = w + ((size_t)ocBase * IC + ic) * 9;
#pragma unroll
        for (int o = 0; o < 8; ++o) {
            const float* wo = wp + (size_t)o * IC * 9;
#pragma unroll
            for (int k = 0; k < 9; ++k)
                acc[o] = fmaf(xv[k], wo[k], acc[o]);
        }
    }

    const int row = r0 + ty, col = c0 + tx;
#pragma unroll
    for (int o = 0; o < 8; ++o) {
        float b = bias[ocBase + o];
        storeV(&out[(((size_t)n * OC + ocBase + o) * H_ + row) * W_ + col], acc[o] + b);
    }
}

// ---------------------------------------------------------------------------
// Per-channel sum / sumsq over (N, H, W). grid.y = C. atomicAdd partials.
// ---------------------------------------------------------------------------
template<typename T>
__global__ __launch_bounds__(256) void stats_kernel(const T* __restrict__ in,
                                                    float* __restrict__ stats,
                                                    int logHW)
{
    const int c = blockIdx.y;
    const int C = gridDim.y;
    const int quads = (N_ << logHW) >> 2;
    const int mask = (1 << logHW) - 1;
    float s = 0.f, s2 = 0.f;
    for (int t = blockIdx.x * 256 + threadIdx.x; t < quads; t += gridDim.x * 256) {
        int idx = t << 2;
        int n = idx >> logHW;
        int off = idx & mask;
        const T* p = in + (((size_t)n * C + c) << logHW) + off;
        float v[4];
        load4(p, v);
#pragma unroll
        for (int j = 0; j < 4; ++j) { s += v[j]; s2 = fmaf(v[j], v[j], s2); }
    }
#pragma unroll
    for (int o = 32; o; o >>= 1) { s += __shfl_down(s, o); s2 += __shfl_down(s2, o); }
    __shared__ float ls[4], ls2[4];
    int wid = threadIdx.x >> 6;
    if ((threadIdx.x & 63) == 0) { ls[wid] = s; ls2[wid] = s2; }
    __syncthreads();
    if (threadIdx.x == 0) {
        float a = 0.f, b = 0.f;
#pragma unroll
        for (int i = 0; i < 4; ++i) { a += ls[i]; b += ls2[i]; }
        atomicAdd(&stats[2 * c], a);
        atomicAdd(&stats[2 * c + 1], b);
    }
}

// ---------------------------------------------------------------------------
// Fused BN (from raw stats) + mish (+ optional fp32 residual). 4 elems/thread.
// ---------------------------------------------------------------------------
template<typename TIN, typename TOUT, bool RES>
__global__ __launch_bounds__(256) void bn_mish_kernel(const TIN* __restrict__ in,
                                                      const float* __restrict__ res,
                                                      TOUT* __restrict__ out,
                                                      const float* __restrict__ stats,
                                                      const float* __restrict__ gamma,
                                                      const float* __restrict__ beta,
                                                      int Cmask, int logHW,
                                                      float invCnt, int total4)
{
    int t = blockIdx.x * 256 + threadIdx.x;
    if (t >= total4) return;
    int idx = t << 2;
    int c = (idx >> logHW) & Cmask;
    float mean = stats[2 * c] * invCnt;
    float var = fmaf(stats[2 * c + 1], invCnt, -mean * mean);
    float scale = rsqrtf(var + EPS_) * gamma[c];
    float shift = fmaf(-mean, scale, beta[c]);
    float v[4];
    load4(in + idx, v);
    float r4[4];
    if (RES) load4(res + idx, r4);
#pragma unroll
    for (int j = 0; j < 4; ++j) {
        float r = mishf(fmaf(v[j], scale, shift));
        if (RES) r += r4[j];
        v[j] = r;
    }
    store4(out + idx, v);
}

// ---------------------------------------------------------------------------
// Fused Haar DWT + 1x1 conv (192->64) over [cH,cV,cD]; writes x_low directly.
// Block: 16 output pixels (one row strip) x all 64 output channels.
// ---------------------------------------------------------------------------
__global__ __launch_bounds__(256) void haar_convh(const __hip_bfloat16* __restrict__ y,
                                                  const float* __restrict__ wh,
                                                  const float* __restrict__ bh,
                                                  float* __restrict__ out_low,
                                                  float* __restrict__ convh_out)
{
    __shared__ float wl[64][193];   // pad: (oc*193+k)%32 = (oc+k)%32 -> 2-way max
    __shared__ float vl[192][17];   // [k][px], pad 17

    const int tid = threadIdx.x;
    for (int i = tid; i < 64 * 192; i += 256)
        wl[i / 192][i % 192] = wh[i];

    const int n = blockIdx.y;
    const int row = blockIdx.x & 127;
    const int j0 = (blockIdx.x >> 7) * 16;

    {
        const int tx = tid & 15, tc = tid >> 4;   // tc in 0..15
#pragma unroll
        for (int ccB = 0; ccB < 64; ccB += 16) {
            int c = ccB + tc;
            const __hip_bfloat16* yp =
                y + ((((size_t)n * 64 + c) * 256 + 2 * row) * 256 + 2 * (j0 + tx));
            ushort2 top = *reinterpret_cast<const ushort2*>(yp);
            ushort2 bot = *reinterpret_cast<const ushort2*>(yp + 256);
            float a = bfbits2f(top.x), b = bfbits2f(top.y);
            float p = bfbits2f(bot.x), q = bfbits2f(bot.y);
            out_low[(((size_t)n * 64 + c) * 128 + row) * 128 + j0 + tx] = 0.5f * (a + b + p + q);
            vl[c][tx]       = 0.5f * (a + b - p - q);
            vl[64 + c][tx]  = 0.5f * (a - b + p - q);
            vl[128 + c][tx] = 0.5f * (a - b - p + q);
        }
    }
    __syncthreads();

    const int px = tid & 15, og = tid >> 4;       // og in 0..15, oc = og + 16m
    float acc[4];
#pragma unroll
    for (int m = 0; m < 4; ++m) acc[m] = bh[og + 16 * m];
    for (int k = 0; k < 192; ++k) {
        float v = vl[k][px];
#pragma unroll
        for (int m = 0; m < 4; ++m)
            acc[m] = fmaf(wl[og + 16 * m][k], v, acc[m]);
    }
#pragma unroll
    for (int m = 0; m < 4; ++m) {
        int oc = og + 16 * m;
        convh_out[(((size_t)n * 64 + oc) * 128 + row) * 128 + j0 + px] = acc[m];
    }
}

// ---------------------------------------------------------------------------
extern "C" void kernel_launch(void* const* d_in, const int* in_sizes, int n_in,
                              void* d_out, int out_size, void* d_ws, size_t ws_size,
                              hipStream_t stream)
{
    (void)in_sizes; (void)n_in; (void)out_size; (void)ws_size;

    const float* x   = (const float*)d_in[0];
    const float* w1  = (const float*)d_in[1];
    const float* b1  = (const float*)d_in[2];
    const float* g1  = (const float*)d_in[3];
    const float* be1 = (const float*)d_in[4];
    const float* w2  = (const float*)d_in[5];
    const float* b2  = (const float*)d_in[6];
    const float* g2  = (const float*)d_in[7];
    const float* be2 = (const float*)d_in[8];
    const float* wh  = (const float*)d_in[9];
    const float* bh  = (const float*)d_in[10];
    const float* gh  = (const float*)d_in[11];
    const float* beh = (const float*)d_in[12];

    float* out = (float*)d_out;
    char* ws = (char*)d_ws;

    // workspace layout (total 201,326,592 B):
    //   [0, 134217728)          h1  (8,128,256,256) bf16   (conv1 out, then mish(bn) in-place)
    //   [134217728, 201326592)  y   (8,64,256,256)  bf16   (conv2 out, then mish(bn)+res in-place)
    // stats: stats1/stats2 live in d_out (overwritten later, after consumption);
    //        statsH at ws head (h1 dead by then).
    __hip_bfloat16* h1  = (__hip_bfloat16*)ws;
    __hip_bfloat16* c2o = (__hip_bfloat16*)(ws + 134217728);
    float* stats1 = out;            // 256 floats, consumed before x_low written
    float* stats2 = out + 256;      // 128 floats, consumed before x_low written
    float* statsH = (float*)ws;     // 128 floats, h1 region dead after conv2
    float* out_high = out + 8388608;

    hipMemsetAsync(stats1, 0, 2048, stream);

    // conv1: x (fp32) -> h1 raw (bf16)
    conv3x3<64, 128, float, __hip_bfloat16>
        <<<dim3(256, 16, N_), 256, 0, stream>>>(x, w1, b1, h1);
    // stats over conv1 out
    stats_kernel<__hip_bfloat16><<<dim3(64, 128), 256, 0, stream>>>(h1, stats1, 16);
    // bn+mish in-place
    bn_mish_kernel<__hip_bfloat16, __hip_bfloat16, false>
        <<<65536, 256, 0, stream>>>(h1, nullptr, h1, stats1, g1, be1, 127, 16,
                                    1.f / 524288.f, 16777216);
    // conv2: h1 (bf16) -> c2o raw (bf16)
    conv3x3<128, 64, __hip_bfloat16, __hip_bfloat16>
        <<<dim3(256, 8, N_), 256, 0, stream>>>(h1, w2, b2, c2o);
    hipMemsetAsync(statsH, 0, 1024, stream);   // h1 region dead now
    // stats over conv2 out
    stats_kernel<__hip_bfloat16><<<dim3(64, 64), 256, 0, stream>>>(c2o, stats2, 16);
    // bn+mish+residual -> y (in-place bf16)
    bn_mish_kernel<__hip_bfloat16, __hip_bfloat16, true>
        <<<32768, 256, 0, stream>>>(c2o, x, c2o, stats2, g2, be2, 63, 16,
                                    1.f / 524288.f, 8388608);
    // haar + 1x1 conv: y -> x_low (d_out first half), convh raw (d_out second half)
    haar_convh<<<dim3(1024, N_), 256, 0, stream>>>(c2o, wh, bh, out, out_high);
    // stats over convh out
    stats_kernel<float><<<dim3(16, 64), 256, 0, stream>>>(out_high, statsH, 14);
    // bn+mish in-place -> final x_high
    bn_mish_kernel<float, float, false>
        <<<8192, 256, 0, stream>>>(out_high, nullptr, out_high, statsH, gh, beh, 63, 14,
                                   1.f / 131072.f, 2097152);
}

// Round 2
// 837.308 us; speedup vs baseline: 4.6127x; 4.6127x over previous
//
#include <hip/hip_runtime.h>
#include <hip/hip_bf16.h>

#define DEV static __device__ __forceinline__

typedef short v8s __attribute__((ext_vector_type(8)));
typedef float v4f __attribute__((ext_vector_type(4)));
typedef unsigned short v4u __attribute__((ext_vector_type(4)));

constexpr int N_  = 8;
constexpr float EPS_ = 1e-5f;

// device-global scratch (ws is exactly full with xh + h1)
__device__ __align__(16) unsigned short g_wT1[9*128*64];   // [tap][oc][ic] bf16
__device__ __align__(16) unsigned short g_wT2[9*64*128];
__device__ __align__(16) float g_stats[512];               // s1[0:256) s2[256:384) sH[384:512)
__device__ __align__(16) unsigned short g_zero[64];        // zero page for OOB staging

DEV float bfbits2f(unsigned short u) { return __uint_as_float(((unsigned)u) << 16); }
DEV unsigned short f2bfbits(float f) {
    __hip_bfloat16 h = __float2bfloat16(f);
    unsigned short b;
    __builtin_memcpy(&b, &h, 2);
    return b;
}

DEV float mishf(float v) {
    // mish(v) = v * tanh(softplus(v)) = v * t(t+2) / (t(t+2)+2),  t = e^v
    float t = __expf(fminf(v, 30.f));
    float num = fmaf(t, t, 2.f * t);
    return v * num * __builtin_amdgcn_rcpf(num + 2.f);
}

DEV void gll16(const unsigned short* g, unsigned short* l) {
    __builtin_amdgcn_global_load_lds(
        (const __attribute__((address_space(1))) unsigned int*)g,
        (__attribute__((address_space(3))) unsigned int*)l,
        16, 0, 0);
}

// ---------------------------------------------------------------------------
// prep: reorder conv weights to [tap][oc][ic] bf16, zero stats + zero page
// ---------------------------------------------------------------------------
__global__ __launch_bounds__(256) void prep(const float* __restrict__ w1,
                                            const float* __restrict__ w2)
{
    int idx = blockIdx.x * 256 + threadIdx.x;
    if (idx < 512) g_stats[idx] = 0.f;
    if (idx < 64) g_zero[idx] = 0;
    if (idx < 73728) {
        {   // wT1: [tap][128 oc][64 ic]
            int tap = idx / 8192, rem = idx & 8191, oc = rem >> 6, ic = rem & 63;
            g_wT1[idx] = f2bfbits(w1[(oc * 64 + ic) * 9 + tap]);
        }
        {   // wT2: [tap][64 oc][128 ic]
            int tap = idx / 8192, rem = idx & 8191, oc = rem >> 7, ic = rem & 127;
            g_wT2[idx] = f2bfbits(w2[(oc * 128 + ic) * 9 + tap]);
        }
    }
}

// ---------------------------------------------------------------------------
// transpose x: NCHW f32 -> NHWC bf16
// ---------------------------------------------------------------------------
__global__ __launch_bounds__(256) void transpose_x(const float* __restrict__ x,
                                                   unsigned short* __restrict__ xh)
{
    __shared__ float t[64][65];
    const int tid = threadIdx.x;
    const int bid = blockIdx.x;
    const int n = bid >> 10, pb = bid & 1023;
    const size_t pix0 = (size_t)pb * 64;
    const float* xb = x + ((size_t)n << 22) + pix0;
#pragma unroll
    for (int cb = 0; cb < 4; ++cb) {
        int c = (tid >> 4) + cb * 16;
        int p = (tid & 15) * 4;
        float4 v = *(const float4*)(xb + ((size_t)c << 16) + p);
        t[c][p] = v.x; t[c][p+1] = v.y; t[c][p+2] = v.z; t[c][p+3] = v.w;
    }
    __syncthreads();
    unsigned short* ob = xh + (((size_t)n << 16) + pix0) * 64;
#pragma unroll
    for (int pb2 = 0; pb2 < 2; ++pb2) {
        int p = (tid >> 3) + pb2 * 32;
        int c0 = (tid & 7) * 8;
        v8s r;
#pragma unroll
        for (int i = 0; i < 8; ++i) r[i] = (short)f2bfbits(t[c0 + i][p]);
        *(v8s*)(ob + (size_t)p * 64 + c0) = r;
    }
}

// ---------------------------------------------------------------------------
// MFMA implicit-GEMM 3x3 conv, pad=1, NHWC bf16.
// Block: 512 thr = 8 waves. Block tile: 64 oc x 128 pix (one half W-row).
// Wave tile: 32 oc x 32 pix. Weights resident in VGPRs (av[9][2][2]).
// X tile [3 rows][130 cols][64 ic] in LDS via global_load_lds, 16B-chunk
// XOR-swizzled (k ^= lc&7) against the 128B-stride bank conflict.
// ---------------------------------------------------------------------------
template<int IC_T, int OC_T, bool ACCUM, int WSEL>
__global__ __launch_bounds__(512, 2) void convMFMA(const unsigned short* __restrict__ in,
                                                   unsigned short* __restrict__ outp,
                                                   const int icoff, const int nTiles)
{
    __shared__ __align__(16) unsigned short Xs[3 * 130 * 64];   // 49920 B; also C-tile
    const unsigned short* wT = (WSEL == 0) ? g_wT1 : g_wT2;

    const int tid  = threadIdx.x;
    const int lane = tid & 63;
    const int wv   = tid >> 6;            // 0..7
    constexpr int NOCB = OC_T / 64;
    const int ocg = (NOCB == 2) ? ((int)blockIdx.x & 1) : 0;
    const int pg  = (NOCB == 2) ? ((int)blockIdx.x >> 1) : (int)blockIdx.x;
    const int NPG = (int)gridDim.x / NOCB;

    const int ocw = wv >> 2;              // oc 32-half within block's 64
    const int wp  = (wv & 3) * 32;        // wave pixel offset
    const int l15 = lane & 15, kg = lane >> 4;

    // ---- weights -> VGPRs: av[tap][ics][sub], A row = l15, k = kg*8..+7
    v8s av[9][2][2];
    {
        const unsigned short* wb =
            wT + ((size_t)(ocg * 64 + ocw * 32 + l15)) * IC_T + icoff + kg * 8;
#pragma unroll
        for (int tap = 0; tap < 9; ++tap)
#pragma unroll
            for (int ics = 0; ics < 2; ++ics)
#pragma unroll
                for (int sub = 0; sub < 2; ++sub)
                    av[tap][ics][sub] =
                        *(const v8s*)(wb + ((size_t)tap * OC_T + sub * 16) * IC_T + ics * 32);
    }

    for (int t = 0; t < nTiles; ++t) {
        const int pt   = pg + NPG * t;                 // 0..4095
        const int n    = pt >> 9;
        const int hrow = (pt >> 1) & 255;
        const int wblk = pt & 1;
        const int w0   = wblk * 128;
        const size_t pixbase = ((size_t)n << 16) + ((size_t)hrow << 8) + w0;

        __syncthreads();   // protect Xs from previous tile's epilogue reads

        // ---- stage X: 3120 chunks of 16B
        {
            const int cb0 = wv * 64;
#pragma unroll
            for (int it = 0; it < 7; ++it) {
                int cb = it * 512 + cb0;               // wave-uniform chunk base
                int chunk = cb + lane;
                if (chunk < 3120) {
                    int r   = chunk / 1040;
                    int rem = chunk - r * 1040;
                    int lc  = rem >> 3, k = rem & 7;
                    int gr  = hrow - 1 + r;
                    int gc  = w0 - 1 + lc;
                    const unsigned short* src;
                    if (((unsigned)gr < 256u) & ((unsigned)gc < 256u))
                        src = in + ((((size_t)n << 16) + ((size_t)gr << 8) + gc) * IC_T)
                                 + icoff + ((k ^ (lc & 7)) << 3);
                    else
                        src = g_zero;
                    gll16(src, Xs + (size_t)cb * 8);
                }
            }
        }
        __syncthreads();   // drains vmcnt

        // ---- MFMA k-loop: 9 taps x 2 ic-subgroups
        v4f acc[2][2];
        {
            v4f z = {0.f, 0.f, 0.f, 0.f};
            acc[0][0] = z; acc[0][1] = z; acc[1][0] = z; acc[1][1] = z;
        }
#pragma unroll
        for (int tap = 0; tap < 9; ++tap) {
            const int dyy = tap / 3, dxx = tap % 3;
            const int lc0 = wp + l15 + dxx;
#pragma unroll
            for (int ics = 0; ics < 2; ++ics) {
                const int off0 = ((dyy * 130 + lc0) * 8 + ((ics * 4 + kg) ^ (lc0 & 7))) * 8;
                v8s b0 = *(const v8s*)(Xs + off0);
                v8s b1 = *(const v8s*)(Xs + off0 + 16 * 64);   // lc0+16: same (lc&7)
                acc[0][0] = __builtin_amdgcn_mfma_f32_16x16x32_bf16(av[tap][ics][0], b0, acc[0][0], 0, 0, 0);
                acc[1][0] = __builtin_amdgcn_mfma_f32_16x16x32_bf16(av[tap][ics][1], b0, acc[1][0], 0, 0, 0);
                acc[0][1] = __builtin_amdgcn_mfma_f32_16x16x32_bf16(av[tap][ics][0], b1, acc[0][1], 0, 0, 0);
                acc[1][1] = __builtin_amdgcn_mfma_f32_16x16x32_bf16(av[tap][ics][1], b1, acc[1][1], 0, 0, 0);
            }
        }

        // ---- epilogue: acc -> CLDS [128 pix][80 oc-pad] -> global (coalesced)
        __syncthreads();
        unsigned short* C = Xs;
#pragma unroll
        for (int sub = 0; sub < 2; ++sub)
#pragma unroll
            for (int ps = 0; ps < 2; ++ps) {
                int px  = wp + ps * 16 + l15;
                int ocb = ocw * 32 + sub * 16 + kg * 4;
                v4f a = acc[sub][ps];
                v4u pk;
#pragma unroll
                for (int r = 0; r < 4; ++r) pk[r] = f2bfbits(a[r]);
                *(v4u*)(C + px * 80 + ocb) = pk;
            }
        __syncthreads();
#pragma unroll
        for (int it = 0; it < 2; ++it) {
            int ch = it * 512 + tid;                    // 0..1023
            int pixl = ch >> 3, occ = ch & 7;
            v8s v = *(const v8s*)(C + pixl * 80 + occ * 8);
            size_t gaddr = (pixbase + pixl) * OC_T + ocg * 64 + occ * 8;
            if (ACCUM) {
                v8s pv = *(const v8s*)(outp + gaddr);
#pragma unroll
                for (int j = 0; j < 8; ++j)
                    v[j] = (short)f2bfbits(bfbits2f((unsigned short)v[j]) +
                                           bfbits2f((unsigned short)pv[j]));
            }
            *(v8s*)(outp + gaddr) = v;
        }
    }
}

// ---------------------------------------------------------------------------
// per-channel stats over NHWC bf16 [P][C]
// ---------------------------------------------------------------------------
template<int C, int OFF>
__global__ __launch_bounds__(256) void statsN(const unsigned short* __restrict__ in, int P)
{
    constexpr int G = C / 8;
    constexpr int LG = (G == 16) ? 4 : 3;
    __shared__ float red[256 * 8];
    const int tid = threadIdx.x;
    const int cg = tid & (G - 1);
    float s[8], q[8];
#pragma unroll
    for (int j = 0; j < 8; ++j) { s[j] = 0.f; q[j] = 0.f; }
    const int tot = P * G;
    const int stride = gridDim.x * 256;
    for (int i = blockIdx.x * 256 + tid; i < tot; i += stride) {
        const int p = i >> LG;
        v8s v = *(const v8s*)(in + (size_t)p * C + cg * 8);
#pragma unroll
        for (int j = 0; j < 8; ++j) {
            float f = bfbits2f((unsigned short)v[j]);
            s[j] += f; q[j] = fmaf(f, f, q[j]);
        }
    }
#pragma unroll
    for (int j = 0; j < 8; ++j) red[tid * 8 + j] = s[j];
    __syncthreads();
    for (int st = (256 / G) >> 1; st > 0; st >>= 1) {
        if ((tid >> LG) < st)
#pragma unroll
            for (int j = 0; j < 8; ++j) red[tid * 8 + j] += red[(tid + st * G) * 8 + j];
        __syncthreads();
    }
    if (tid < G)
#pragma unroll
        for (int j = 0; j < 8; ++j) atomicAdd(&g_stats[OFF + 2 * (cg * 8 + j)], red[tid * 8 + j]);
    __syncthreads();
#pragma unroll
    for (int j = 0; j < 8; ++j) red[tid * 8 + j] = q[j];
    __syncthreads();
    for (int st = (256 / G) >> 1; st > 0; st >>= 1) {
        if ((tid >> LG) < st)
#pragma unroll
            for (int j = 0; j < 8; ++j) red[tid * 8 + j] += red[(tid + st * G) * 8 + j];
        __syncthreads();
    }
    if (tid < G)
#pragma unroll
        for (int j = 0; j < 8; ++j) atomicAdd(&g_stats[OFF + 2 * (cg * 8 + j) + 1], red[tid * 8 + j]);
}

// ---------------------------------------------------------------------------
// BN + mish (+ residual) over NHWC bf16, 8 elems/thread
// ---------------------------------------------------------------------------
template<int C, bool RES, int OFF>
__global__ __launch_bounds__(256) void bnN(const unsigned short* __restrict__ in,
                                           const unsigned short* __restrict__ res,
                                           unsigned short* __restrict__ outp,
                                           const float* __restrict__ gam,
                                           const float* __restrict__ bet, int total8)
{
    const int t0 = blockIdx.x * 256 + threadIdx.x;
    const int c0 = (t0 * 8) & (C - 1);
    constexpr float INV = 1.f / 524288.f;
    float sc[8], sh[8];
#pragma unroll
    for (int j = 0; j < 8; ++j) {
        int c = c0 + j;
        float m  = g_stats[OFF + 2 * c] * INV;
        float va = fmaf(g_stats[OFF + 2 * c + 1], INV, -m * m);
        sc[j] = rsqrtf(va + EPS_) * gam[c];
        sh[j] = fmaf(-m, sc[j], bet[c]);
    }
    const int stride = gridDim.x * 256;
    for (int i = t0; i < total8; i += stride) {
        v8s v = *(const v8s*)(in + (size_t)i * 8);
        v8s rr;
        if (RES) rr = *(const v8s*)(res + (size_t)i * 8);
        v8s o;
#pragma unroll
        for (int j = 0; j < 8; ++j) {
            float f = mishf(fmaf(bfbits2f((unsigned short)v[j]), sc[j], sh[j]));
            if (RES) f += bfbits2f((unsigned short)rr[j]);
            o[j] = (short)f2bfbits(f);
        }
        *(v8s*)(outp + (size_t)i * 8) = o;
    }
}

// ---------------------------------------------------------------------------
// Haar DWT + 1x1 conv (192->64): y NHWC bf16 -> x_low NCHW f32 + convh NCHW f32
// ---------------------------------------------------------------------------
__global__ __launch_bounds__(256) void haar_convh(const unsigned short* __restrict__ y,
                                                  const float* __restrict__ wh,
                                                  float* __restrict__ out_low,
                                                  float* __restrict__ convh_out)
{
    __shared__ float wl[64][193];
    __shared__ float vl[192][17];

    const int tid = threadIdx.x;
    for (int i = tid; i < 64 * 192; i += 256)
        wl[i / 192][i % 192] = wh[i];

    const int n = blockIdx.y;
    const int row = blockIdx.x & 127;
    const int j0 = (blockIdx.x >> 7) * 16;

    {
        const int tc = tid & 15, tx = tid >> 4;
        const size_t base = ((((size_t)n * 256 + 2 * row) * 256) + 2 * (j0 + tx)) * 64 + tc * 4;
        v4u a4 = *(const v4u*)(y + base);
        v4u b4 = *(const v4u*)(y + base + 64);
        v4u p4 = *(const v4u*)(y + base + 16384);
        v4u q4 = *(const v4u*)(y + base + 16384 + 64);
#pragma unroll
        for (int i = 0; i < 4; ++i) {
            const int c = tc * 4 + i;
            float a = bfbits2f(a4[i]), b = bfbits2f(b4[i]);
            float p = bfbits2f(p4[i]), q = bfbits2f(q4[i]);
            out_low[(((size_t)n * 64 + c) * 128 + row) * 128 + j0 + tx] = 0.5f * (a + b + p + q);
            vl[c][tx]       = 0.5f * (a + b - p - q);
            vl[64 + c][tx]  = 0.5f * (a - b + p - q);
            vl[128 + c][tx] = 0.5f * (a - b - p + q);
        }
    }
    __syncthreads();

    const int px = tid & 15, og = tid >> 4;
    float acc[4] = {0.f, 0.f, 0.f, 0.f};
    for (int k = 0; k < 192; ++k) {
        float v = vl[k][px];
#pragma unroll
        for (int m = 0; m < 4; ++m)
            acc[m] = fmaf(wl[og + 16 * m][k], v, acc[m]);
    }
#pragma unroll
    for (int m = 0; m < 4; ++m)
        convh_out[(((size_t)n * 64 + og + 16 * m) * 128 + row) * 128 + j0 + px] = acc[m];
}

// ---------------------------------------------------------------------------
// f32 NCHW stats + BN+mish (for the 1x1-conv output)
// ---------------------------------------------------------------------------
__global__ __launch_bounds__(256) void statsF(const float* __restrict__ in, int stOff, int logHW)
{
    const int c = blockIdx.y;
    const int C = gridDim.y;
    const int quads = (N_ << logHW) >> 2;
    const int mask = (1 << logHW) - 1;
    float s = 0.f, s2 = 0.f;
    for (int t = blockIdx.x * 256 + threadIdx.x; t < quads; t += gridDim.x * 256) {
        int idx = t << 2;
        int n = idx >> logHW;
        int off = idx & mask;
        const float* p = in + (((size_t)n * C + c) << logHW) + off;
        float4 v = *(const float4*)p;
        s += v.x + v.y + v.z + v.w;
        s2 = fmaf(v.x, v.x, s2); s2 = fmaf(v.y, v.y, s2);
        s2 = fmaf(v.z, v.z, s2); s2 = fmaf(v.w, v.w, s2);
    }
#pragma unroll
    for (int o = 32; o; o >>= 1) { s += __shfl_down(s, o); s2 += __shfl_down(s2, o); }
    __shared__ float ls[4], ls2[4];
    int wid = threadIdx.x >> 6;
    if ((threadIdx.x & 63) == 0) { ls[wid] = s; ls2[wid] = s2; }
    __syncthreads();
    if (threadIdx.x == 0) {
        float a = 0.f, b = 0.f;
#pragma unroll
        for (int i = 0; i < 4; ++i) { a += ls[i]; b += ls2[i]; }
        atomicAdd(&g_stats[stOff + 2 * c], a);
        atomicAdd(&g_stats[stOff + 2 * c + 1], b);
    }
}

__global__ __launch_bounds__(256) void bnF(const float* __restrict__ in,
                                           float* __restrict__ outp, int stOff,
                                           const float* __restrict__ gam,
                                           const float* __restrict__ bet,
                                           int Cmask, int logHW, float invCnt, int total4)
{
    int t = blockIdx.x * 256 + threadIdx.x;
    if (t >= total4) return;
    int idx = t << 2;
    int c = (idx >> logHW) & Cmask;
    float mean = g_stats[stOff + 2 * c] * invCnt;
    float var = fmaf(g_stats[stOff + 2 * c + 1], invCnt, -mean * mean);
    float scale = rsqrtf(var + EPS_) * gam[c];
    float shift = fmaf(-mean, scale, bet[c]);
    float4 v = *(const float4*)(in + idx);
    v.x = mishf(fmaf(v.x, scale, shift));
    v.y = mishf(fmaf(v.y, scale, shift));
    v.z = mishf(fmaf(v.z, scale, shift));
    v.w = mishf(fmaf(v.w, scale, shift));
    *(float4*)(outp + idx) = v;
}

// ---------------------------------------------------------------------------
extern "C" void kernel_launch(void* const* d_in, const int* in_sizes, int n_in,
                              void* d_out, int out_size, void* d_ws, size_t ws_size,
                              hipStream_t stream)
{
    (void)in_sizes; (void)n_in; (void)out_size; (void)ws_size;

    const float* x   = (const float*)d_in[0];
    const float* w1  = (const float*)d_in[1];
    const float* g1  = (const float*)d_in[3];
    const float* be1 = (const float*)d_in[4];
    const float* w2  = (const float*)d_in[5];
    const float* g2  = (const float*)d_in[7];
    const float* be2 = (const float*)d_in[8];
    const float* wh  = (const float*)d_in[9];
    const float* gh  = (const float*)d_in[11];
    const float* beh = (const float*)d_in[12];
    // biases b1,b2,bh are mathematically absorbed by the following BatchNorms.

    char* ws = (char*)d_ws;
    unsigned short* xh = (unsigned short*)ws;                     // x NHWC bf16 [524288][64]
    unsigned short* h1 = (unsigned short*)(ws + 67108864);        // conv1 out NHWC bf16 [524288][128]
    unsigned short* y  = h1;                                      // y overwrites h1 (dead after conv2)
    unsigned short* c2 = (unsigned short*)d_out;                  // conv2 raw NHWC bf16 [524288][64]
    float* out_low = (float*)d_out;
    float* convh   = (float*)d_out + 8388608;

    prep<<<288, 256, 0, stream>>>(w1, w2);
    transpose_x<<<8192, 256, 0, stream>>>(x, xh);

    // conv1: xh -> h1 (raw)
    convMFMA<64, 128, false, 0><<<1024, 512, 0, stream>>>(xh, h1, 0, 8);
    statsN<128, 0><<<256, 256, 0, stream>>>(h1, 524288);
    bnN<128, false, 0><<<1024, 256, 0, stream>>>(h1, nullptr, h1, g1, be1, 8388608);

    // conv2: two 64-ic passes
    convMFMA<128, 64, false, 1><<<1024, 512, 0, stream>>>(h1, c2, 0, 4);
    convMFMA<128, 64, true, 1><<<1024, 512, 0, stream>>>(h1, c2, 64, 4);
    statsN<64, 256><<<256, 256, 0, stream>>>(c2, 524288);
    bnN<64, true, 256><<<1024, 256, 0, stream>>>(c2, xh, y, g2, be2, 4194304);

    // haar + 1x1 conv
    haar_convh<<<dim3(1024, N_), 256, 0, stream>>>(y, wh, out_low, convh);
    statsF<<<dim3(16, 64), 256, 0, stream>>>(convh, 384, 14);
    bnF<<<8192, 256, 0, stream>>>(convh, convh, 384, gh, beh, 63, 14, 1.f / 131072.f, 2097152);
}